// Round 1
// baseline (251.868 us; speedup 1.0000x reference)
//
#include <hip/hip_runtime.h>

// Problem constants (match reference setup_inputs)
constexpr int Bc   = 8;
constexpr int Nc   = 2048;   // power of two: row = b*Nc + i, i = row & (Nc-1)
constexpr int DIN  = 5;
constexpr int DHID = 32;

// ---------------------------------------------------------------------------
// Kernel 1: u[b, d, j] = sum_e M[d][e] * s[b, j, e],  M = Qw @ Kw^T (5x5)
// Layout of u is [B][DIN][N] so the main kernel gets coalesced float4 loads.
// ---------------------------------------------------------------------------
__global__ __launch_bounds__(256) void u_precompute(
    const float* __restrict__ s, const float* __restrict__ Qw,
    const float* __restrict__ Kw, float* __restrict__ u)
{
    __shared__ float Msh[DIN * DIN];
    const int tid = threadIdx.x;
    if (tid < DIN * DIN) {
        const int d = tid / DIN, e = tid % DIN;
        float acc = 0.f;
        #pragma unroll
        for (int m = 0; m < DHID; ++m)
            acc = fmaf(Qw[d * DHID + m], Kw[e * DHID + m], acc);
        Msh[tid] = acc;
    }
    __syncthreads();
    const int g = blockIdx.x * 256 + tid;       // g in [0, B*N)
    if (g >= Bc * Nc) return;
    const int b = g >> 11;                       // g / Nc
    const int j = g & (Nc - 1);
    float sv[DIN];
    #pragma unroll
    for (int e = 0; e < DIN; ++e) sv[e] = s[(size_t)g * DIN + e];
    #pragma unroll
    for (int d = 0; d < DIN; ++d) {
        float acc = 0.f;
        #pragma unroll
        for (int e = 0; e < DIN; ++e) acc = fmaf(Msh[d * DIN + e], sv[e], acc);
        u[((size_t)b * DIN + d) * Nc + j] = acc;
    }
}

// ---------------------------------------------------------------------------
// Kernel 2 (main): one block per output row (b,i). Each thread owns 8 j's as
// two float4 groups; single pass over G, row-sum via shuffle+LDS reduce,
// normalize in registers, one coalesced float4 store pass.
// ---------------------------------------------------------------------------
__global__ __launch_bounds__(256) void att_row_u(
    const float* __restrict__ s, const float* __restrict__ G,
    const float* __restrict__ u, float* __restrict__ out, long gbs)
{
    const int row = blockIdx.x;          // b*Nc + i
    const int b   = row >> 11;
    const int i   = row & (Nc - 1);
    const int tid = threadIdx.x;

    float si[DIN];
    #pragma unroll
    for (int d = 0; d < DIN; ++d) si[d] = s[(size_t)row * DIN + d];

    const float* gRow = G + (size_t)b * gbs + (size_t)i * Nc;
    const float* ub   = u + (size_t)b * DIN * Nc;
    float*       oRow = out + (size_t)row * Nc;

    float a[2][4];
    float lsum = 0.f;
    #pragma unroll
    for (int it = 0; it < 2; ++it) {
        const int j0 = it * 1024 + tid * 4;
        const float4 g4 = *reinterpret_cast<const float4*>(gRow + j0);
        float vx = 0.f, vy = 0.f, vz = 0.f, vw = 0.f;
        #pragma unroll
        for (int d = 0; d < DIN; ++d) {
            const float4 ud = *reinterpret_cast<const float4*>(ub + (size_t)d * Nc + j0);
            vx = fmaf(si[d], ud.x, vx);
            vy = fmaf(si[d], ud.y, vy);
            vz = fmaf(si[d], ud.z, vz);
            vw = fmaf(si[d], ud.w, vw);
        }
        a[it][0] = vx * vx * g4.x;
        a[it][1] = vy * vy * g4.y;
        a[it][2] = vz * vz * g4.z;
        a[it][3] = vw * vw * g4.w;
        lsum += (a[it][0] + a[it][1]) + (a[it][2] + a[it][3]);
    }

    // wave64 reduce, then cross-wave via LDS (4 waves)
    #pragma unroll
    for (int off = 32; off > 0; off >>= 1)
        lsum += __shfl_xor(lsum, off, 64);
    __shared__ float wpart[4];
    if ((tid & 63) == 0) wpart[tid >> 6] = lsum;
    __syncthreads();
    const float total = (wpart[0] + wpart[1]) + (wpart[2] + wpart[3]);
    const float inv = 1.0f / (total + 0.001f);

    #pragma unroll
    for (int it = 0; it < 2; ++it) {
        const int j0 = it * 1024 + tid * 4;
        float4 o;
        o.x = a[it][0] * inv;
        o.y = a[it][1] * inv;
        o.z = a[it][2] * inv;
        o.w = a[it][3] * inv;
        *reinterpret_cast<float4*>(oRow + j0) = o;
    }
}

// ---------------------------------------------------------------------------
// Fallback (no workspace needed): compute M per block, w_i = s_i^T M once,
// then a_ij = (w_i . s_j)^2 * G_ij reading s_j directly (L1/L2-resident).
// ---------------------------------------------------------------------------
__global__ __launch_bounds__(256) void att_row_direct(
    const float* __restrict__ s, const float* __restrict__ G,
    const float* __restrict__ Qw, const float* __restrict__ Kw,
    float* __restrict__ out, long gbs)
{
    __shared__ float Msh[DIN * DIN];
    __shared__ float wpart[4];
    const int tid = threadIdx.x;
    if (tid < DIN * DIN) {
        const int d = tid / DIN, e = tid % DIN;
        float acc = 0.f;
        #pragma unroll
        for (int m = 0; m < DHID; ++m)
            acc = fmaf(Qw[d * DHID + m], Kw[e * DHID + m], acc);
        Msh[tid] = acc;
    }
    __syncthreads();

    const int row = blockIdx.x;
    const int b   = row >> 11;
    const int i   = row & (Nc - 1);

    // w[d] = sum_e s_i[e] * M[e][d]
    float w[DIN];
    {
        float si[DIN];
        #pragma unroll
        for (int e = 0; e < DIN; ++e) si[e] = s[(size_t)row * DIN + e];
        #pragma unroll
        for (int d = 0; d < DIN; ++d) {
            float acc = 0.f;
            #pragma unroll
            for (int e = 0; e < DIN; ++e) acc = fmaf(si[e], Msh[e * DIN + d], acc);
            w[d] = acc;
        }
    }

    const float* gRow = G + (size_t)b * gbs + (size_t)i * Nc;
    const float* sb   = s + (size_t)b * Nc * DIN;
    float*       oRow = out + (size_t)row * Nc;

    float a[2][4];
    float lsum = 0.f;
    #pragma unroll
    for (int it = 0; it < 2; ++it) {
        const int j0 = it * 1024 + tid * 4;
        const float4 g4 = *reinterpret_cast<const float4*>(gRow + j0);
        float v[4];
        #pragma unroll
        for (int c = 0; c < 4; ++c) {
            const float* sj = sb + (size_t)(j0 + c) * DIN;
            float acc = 0.f;
            #pragma unroll
            for (int d = 0; d < DIN; ++d) acc = fmaf(w[d], sj[d], acc);
            v[c] = acc;
        }
        a[it][0] = v[0] * v[0] * g4.x;
        a[it][1] = v[1] * v[1] * g4.y;
        a[it][2] = v[2] * v[2] * g4.z;
        a[it][3] = v[3] * v[3] * g4.w;
        lsum += (a[it][0] + a[it][1]) + (a[it][2] + a[it][3]);
    }

    #pragma unroll
    for (int off = 32; off > 0; off >>= 1)
        lsum += __shfl_xor(lsum, off, 64);
    if ((tid & 63) == 0) wpart[tid >> 6] = lsum;
    __syncthreads();
    const float total = (wpart[0] + wpart[1]) + (wpart[2] + wpart[3]);
    const float inv = 1.0f / (total + 0.001f);

    #pragma unroll
    for (int it = 0; it < 2; ++it) {
        const int j0 = it * 1024 + tid * 4;
        float4 o;
        o.x = a[it][0] * inv;
        o.y = a[it][1] * inv;
        o.z = a[it][2] * inv;
        o.w = a[it][3] * inv;
        *reinterpret_cast<float4*>(oRow + j0) = o;
    }
}

extern "C" void kernel_launch(void* const* d_in, const int* in_sizes, int n_in,
                              void* d_out, int out_size, void* d_ws, size_t ws_size,
                              hipStream_t stream)
{
    const float* s  = (const float*)d_in[0];
    const float* G  = (const float*)d_in[1];
    const float* Qw = (const float*)d_in[2];
    const float* Kw = (const float*)d_in[3];
    float* out = (float*)d_out;

    // Gmat may be [N,N] (broadcast) or [B,N,N]
    const long gbs = (in_sizes[1] == Nc * Nc) ? 0L : (long)Nc * Nc;

    const size_t uBytes = (size_t)Bc * DIN * Nc * sizeof(float);
    if (ws_size >= uBytes) {
        float* u = (float*)d_ws;
        u_precompute<<<(Bc * Nc + 255) / 256, 256, 0, stream>>>(s, Qw, Kw, u);
        att_row_u<<<Bc * Nc, 256, 0, stream>>>(s, G, u, out, gbs);
    } else {
        att_row_direct<<<Bc * Nc, 256, 0, stream>>>(s, G, Qw, Kw, out, gbs);
    }
}

// Round 6
// 241.713 us; speedup vs baseline: 1.0420x; 1.0420x over previous
//
#include <hip/hip_runtime.h>

// Problem constants (match reference setup_inputs)
constexpr int Bc   = 8;
constexpr int Nc   = 2048;   // power of two: global row = b*Nc + i
constexpr int DIN  = 5;
constexpr int DHID = 32;
constexpr int ROWS = 4;      // rows per block (all share one b: Nc % ROWS == 0)

// clang vector type usable with __builtin_nontemporal_store
typedef float vf4 __attribute__((ext_vector_type(4)));

// ---------------------------------------------------------------------------
// Kernel 1: u[b, d, j] = sum_e M[d][e] * s[b, j, e],  M = Qw @ Kw^T (5x5)
// Layout [B][DIN][N] -> coalesced float4 streams in the main kernel.
// ---------------------------------------------------------------------------
__global__ __launch_bounds__(256) void u_precompute(
    const float* __restrict__ s, const float* __restrict__ Qw,
    const float* __restrict__ Kw, float* __restrict__ u)
{
    __shared__ float Msh[DIN * DIN];
    const int tid = threadIdx.x;
    if (tid < DIN * DIN) {
        const int d = tid / DIN, e = tid % DIN;
        float acc = 0.f;
        #pragma unroll
        for (int m = 0; m < DHID; ++m)
            acc = fmaf(Qw[d * DHID + m], Kw[e * DHID + m], acc);
        Msh[tid] = acc;
    }
    __syncthreads();
    const int g = blockIdx.x * 256 + tid;       // g in [0, B*N)
    if (g >= Bc * Nc) return;
    const int b = g >> 11;
    const int j = g & (Nc - 1);
    float sv[DIN];
    #pragma unroll
    for (int e = 0; e < DIN; ++e) sv[e] = s[(size_t)g * DIN + e];
    #pragma unroll
    for (int d = 0; d < DIN; ++d) {
        float acc = 0.f;
        #pragma unroll
        for (int e = 0; e < DIN; ++e) acc = fmaf(Msh[d * DIN + e], sv[e], acc);
        u[((size_t)b * DIN + d) * Nc + j] = acc;
    }
}

// ---------------------------------------------------------------------------
// Main kernel: ROWS=4 rows per 256-thread block. Each thread owns 8 j's
// (two float4 chunks) per row. The 5 u-streams are loaded ONCE per chunk and
// reused across the 4 rows (4x less L2 traffic for u). Output stores are
// non-temporal so the 134 MB out stream doesn't evict G from Infinity Cache.
// ---------------------------------------------------------------------------
__global__ __launch_bounds__(256, 4) void att_rows4(
    const float* __restrict__ s, const float* __restrict__ G,
    const float* __restrict__ u, float* __restrict__ out, long gbs)
{
    const int tid  = threadIdx.x;
    const int row0 = blockIdx.x * ROWS;          // global row (b*Nc + i), 4-aligned
    const int b    = row0 >> 11;
    const int i0   = row0 & (Nc - 1);

    // s_i for the 4 rows (broadcast loads, L2-resident)
    float si[ROWS][DIN];
    #pragma unroll
    for (int r = 0; r < ROWS; ++r)
        #pragma unroll
        for (int d = 0; d < DIN; ++d)
            si[r][d] = s[(size_t)(row0 + r) * DIN + d];

    const float* ub = u + (size_t)b * DIN * Nc;
    const float* gB = G + (size_t)b * gbs;

    float a[ROWS][2][4];
    float psum[ROWS];
    #pragma unroll
    for (int r = 0; r < ROWS; ++r) psum[r] = 0.f;

    #pragma unroll
    for (int c = 0; c < 2; ++c) {
        const int j0 = c * 1024 + tid * 4;
        // load u streams once per chunk
        float4 ud[DIN];
        #pragma unroll
        for (int d = 0; d < DIN; ++d)
            ud[d] = *reinterpret_cast<const float4*>(ub + (size_t)d * Nc + j0);
        #pragma unroll
        for (int r = 0; r < ROWS; ++r) {
            const float4 g4 = *reinterpret_cast<const float4*>(
                gB + (size_t)(i0 + r) * Nc + j0);
            float vx = 0.f, vy = 0.f, vz = 0.f, vw = 0.f;
            #pragma unroll
            for (int d = 0; d < DIN; ++d) {
                vx = fmaf(si[r][d], ud[d].x, vx);
                vy = fmaf(si[r][d], ud[d].y, vy);
                vz = fmaf(si[r][d], ud[d].z, vz);
                vw = fmaf(si[r][d], ud[d].w, vw);
            }
            a[r][c][0] = vx * vx * g4.x;
            a[r][c][1] = vy * vy * g4.y;
            a[r][c][2] = vz * vz * g4.z;
            a[r][c][3] = vw * vw * g4.w;
            psum[r] += (a[r][c][0] + a[r][c][1]) + (a[r][c][2] + a[r][c][3]);
        }
    }

    // per-row block-wide reduction: wave64 shuffle, then LDS across 4 waves
    #pragma unroll
    for (int r = 0; r < ROWS; ++r)
        #pragma unroll
        for (int off = 32; off > 0; off >>= 1)
            psum[r] += __shfl_xor(psum[r], off, 64);

    __shared__ float wpart[4][ROWS];
    if ((tid & 63) == 0) {
        #pragma unroll
        for (int r = 0; r < ROWS; ++r) wpart[tid >> 6][r] = psum[r];
    }
    __syncthreads();

    float inv[ROWS];
    #pragma unroll
    for (int r = 0; r < ROWS; ++r)
        inv[r] = 1.0f / ((wpart[0][r] + wpart[1][r]) +
                         (wpart[2][r] + wpart[3][r]) + 0.001f);

    #pragma unroll
    for (int c = 0; c < 2; ++c) {
        const int j0 = c * 1024 + tid * 4;
        #pragma unroll
        for (int r = 0; r < ROWS; ++r) {
            vf4 o;
            o.x = a[r][c][0] * inv[r];
            o.y = a[r][c][1] * inv[r];
            o.z = a[r][c][2] * inv[r];
            o.w = a[r][c][3] * inv[r];
            __builtin_nontemporal_store(
                o, reinterpret_cast<vf4*>(out + (size_t)(row0 + r) * Nc + j0));
        }
    }
}

// ---------------------------------------------------------------------------
// Fallback (no workspace): single-row blocks, M computed per block.
// ---------------------------------------------------------------------------
__global__ __launch_bounds__(256) void att_row_direct(
    const float* __restrict__ s, const float* __restrict__ G,
    const float* __restrict__ Qw, const float* __restrict__ Kw,
    float* __restrict__ out, long gbs)
{
    __shared__ float Msh[DIN * DIN];
    __shared__ float wpart[4];
    const int tid = threadIdx.x;
    if (tid < DIN * DIN) {
        const int d = tid / DIN, e = tid % DIN;
        float acc = 0.f;
        #pragma unroll
        for (int m = 0; m < DHID; ++m)
            acc = fmaf(Qw[d * DHID + m], Kw[e * DHID + m], acc);
        Msh[tid] = acc;
    }
    __syncthreads();

    const int row = blockIdx.x;
    const int b   = row >> 11;
    const int i   = row & (Nc - 1);

    float w[DIN];
    {
        float si[DIN];
        #pragma unroll
        for (int e = 0; e < DIN; ++e) si[e] = s[(size_t)row * DIN + e];
        #pragma unroll
        for (int d = 0; d < DIN; ++d) {
            float acc = 0.f;
            #pragma unroll
            for (int e = 0; e < DIN; ++e) acc = fmaf(si[e], Msh[e * DIN + d], acc);
            w[d] = acc;
        }
    }

    const float* gRow = G + (size_t)b * gbs + (size_t)i * Nc;
    const float* sb   = s + (size_t)b * Nc * DIN;
    float*       oRow = out + (size_t)row * Nc;

    float a[2][4];
    float lsum = 0.f;
    #pragma unroll
    for (int it = 0; it < 2; ++it) {
        const int j0 = it * 1024 + tid * 4;
        const float4 g4 = *reinterpret_cast<const float4*>(gRow + j0);
        float v[4];
        #pragma unroll
        for (int c = 0; c < 4; ++c) {
            const float* sj = sb + (size_t)(j0 + c) * DIN;
            float acc = 0.f;
            #pragma unroll
            for (int d = 0; d < DIN; ++d) acc = fmaf(w[d], sj[d], acc);
            v[c] = acc;
        }
        a[it][0] = v[0] * v[0] * g4.x;
        a[it][1] = v[1] * v[1] * g4.y;
        a[it][2] = v[2] * v[2] * g4.z;
        a[it][3] = v[3] * v[3] * g4.w;
        lsum += (a[it][0] + a[it][1]) + (a[it][2] + a[it][3]);
    }

    #pragma unroll
    for (int off = 32; off > 0; off >>= 1)
        lsum += __shfl_xor(lsum, off, 64);
    if ((tid & 63) == 0) wpart[tid >> 6] = lsum;
    __syncthreads();
    const float total = (wpart[0] + wpart[1]) + (wpart[2] + wpart[3]);
    const float inv = 1.0f / (total + 0.001f);

    #pragma unroll
    for (int it = 0; it < 2; ++it) {
        const int j0 = it * 1024 + tid * 4;
        vf4 o;
        o.x = a[it][0] * inv;
        o.y = a[it][1] * inv;
        o.z = a[it][2] * inv;
        o.w = a[it][3] * inv;
        __builtin_nontemporal_store(o, reinterpret_cast<vf4*>(oRow + j0));
    }
}

extern "C" void kernel_launch(void* const* d_in, const int* in_sizes, int n_in,
                              void* d_out, int out_size, void* d_ws, size_t ws_size,
                              hipStream_t stream)
{
    const float* s  = (const float*)d_in[0];
    const float* G  = (const float*)d_in[1];
    const float* Qw = (const float*)d_in[2];
    const float* Kw = (const float*)d_in[3];
    float* out = (float*)d_out;

    // Gmat may be [N,N] (broadcast) or [B,N,N]
    const long gbs = (in_sizes[1] == Nc * Nc) ? 0L : (long)Nc * Nc;

    const size_t uBytes = (size_t)Bc * DIN * Nc * sizeof(float);
    if (ws_size >= uBytes) {
        float* u = (float*)d_ws;
        u_precompute<<<(Bc * Nc + 255) / 256, 256, 0, stream>>>(s, Qw, Kw, u);
        att_rows4<<<(Bc * Nc) / ROWS, 256, 0, stream>>>(s, G, u, out, gbs);
    } else {
        att_row_direct<<<Bc * Nc, 256, 0, stream>>>(s, G, Qw, Kw, out, gbs);
    }
}